// Round 2
// baseline (378.833 us; speedup 1.0000x reference)
//
#include <hip/hip_runtime.h>
#include <hip/hip_bf16.h>
#include <stdint.h>

typedef unsigned short u16;
typedef __attribute__((ext_vector_type(8))) __bf16 bf16x8;
typedef __attribute__((ext_vector_type(4))) float f32x4;

#define DEV static __device__ __forceinline__

DEV u16 f32_to_bf16(float f) {
  uint32_t u = __float_as_uint(f);
  u += 0x7fffu + ((u >> 16) & 1u);   // round-to-nearest-even
  return (u16)(u >> 16);
}

DEV void unpack8(uint4 u, float* f) {
  uint32_t a[4] = {u.x, u.y, u.z, u.w};
#pragma unroll
  for (int i = 0; i < 4; ++i) {
    f[2 * i]     = __uint_as_float(a[i] << 16);
    f[2 * i + 1] = __uint_as_float(a[i] & 0xffff0000u);
  }
}

DEV uint4 pack8(const float* f) {
  uint32_t a[4];
#pragma unroll
  for (int i = 0; i < 4; ++i)
    a[i] = (uint32_t)f32_to_bf16(f[2 * i]) | ((uint32_t)f32_to_bf16(f[2 * i + 1]) << 16);
  return make_uint4(a[0], a[1], a[2], a[3]);
}

DEV bf16x8 cvt8(float4 a, float4 b) {
  union { u16 h[8]; bf16x8 v; } u;
  u.h[0] = f32_to_bf16(a.x); u.h[1] = f32_to_bf16(a.y);
  u.h[2] = f32_to_bf16(a.z); u.h[3] = f32_to_bf16(a.w);
  u.h[4] = f32_to_bf16(b.x); u.h[5] = f32_to_bf16(b.y);
  u.h[6] = f32_to_bf16(b.z); u.h[7] = f32_to_bf16(b.w);
  return u.v;
}

// ---------------------------------------------------------------------------
// Kernel 1: weights f32 -> bf16.  wqkv = rows of Wq|Wk|Wv (768x256),
// wob = Wo (256x256).  65536 float4 chunks total.
// ---------------------------------------------------------------------------
__global__ __launch_bounds__(256) void convert_w(
    const float* __restrict__ Wq, const float* __restrict__ Wk,
    const float* __restrict__ Wv, const float* __restrict__ Wo,
    u16* __restrict__ wqkv, u16* __restrict__ wob) {
  int i = blockIdx.x * 256 + threadIdx.x;  // [0, 65536)
  int which = i >> 14;                     // 16384 float4 per 256x256 matrix
  int off4 = i & 16383;
  const float* src; u16* dst;
  if (which == 0)      { src = Wq; dst = wqkv; }
  else if (which == 1) { src = Wk; dst = wqkv + 65536; }
  else if (which == 2) { src = Wv; dst = wqkv + 131072; }
  else                 { src = Wo; dst = wob; }
  float4 v = reinterpret_cast<const float4*>(src)[off4];
  ushort4 o;
  o.x = f32_to_bf16(v.x); o.y = f32_to_bf16(v.y);
  o.z = f32_to_bf16(v.z); o.w = f32_to_bf16(v.w);
  reinterpret_cast<ushort4*>(dst)[off4] = o;
}

// ---------------------------------------------------------------------------
// Kernel 2: QKV projection, ZERO-LDS.  C(65536x768) = bf16(x) @ Wqkv^T + bias.
// Block = 32 rows x 256 cols (4 waves n-split, each wave 32x64, acc[2][4]).
// A-frags read f32 from x and converted in-register (identical rounding to a
// separate convert pass); B-frags read bf16 direct from global (L2-resident).
// No barriers: compiler pipelines the 8-step K loop freely.
// ---------------------------------------------------------------------------
__global__ __launch_bounds__(256) void qkv_gemm2(
    const float* __restrict__ x, const u16* __restrict__ Wqkv,
    const float* __restrict__ bq, const float* __restrict__ bk,
    const float* __restrict__ bv, u16* __restrict__ QKV) {
  const int bn = blockIdx.x;   // 0..2  (Q/K/V block of 256 cols)
  const int bm = blockIdx.y;   // 0..2047 (32-row strips)
  const int lane = threadIdx.x & 63;
  const int wid = threadIdx.x >> 6;
  const int fr = lane & 15;
  const int fq = lane >> 4;
  const int row0 = bm * 32;
  const int colw = wid * 64;             // col offset within the 256-col block

  const float* Ag = x + (size_t)(row0 + fr) * 256 + fq * 8;
  const u16* Bg = Wqkv + ((size_t)bn * 256 + colw + fr) * 256 + fq * 8;

  f32x4 acc[2][4] = {};

  for (int kt = 0; kt < 8; ++kt) {
    bf16x8 af[2], bf[4];
#pragma unroll
    for (int m = 0; m < 2; ++m) {
      const float* p = Ag + (size_t)(m * 16) * 256 + kt * 32;
      float4 u0 = *reinterpret_cast<const float4*>(p);
      float4 u1 = *reinterpret_cast<const float4*>(p + 4);
      af[m] = cvt8(u0, u1);
    }
#pragma unroll
    for (int n = 0; n < 4; ++n)
      bf[n] = *reinterpret_cast<const bf16x8*>(Bg + (size_t)(n * 16) * 256 + kt * 32);
#pragma unroll
    for (int m = 0; m < 2; ++m)
#pragma unroll
      for (int n = 0; n < 4; ++n)
        acc[m][n] = __builtin_amdgcn_mfma_f32_16x16x32_bf16(af[m], bf[n], acc[m][n], 0, 0, 0);
  }

  const float* bias = (bn == 0) ? bq : (bn == 1) ? bk : bv;
  float bv4[4];
#pragma unroll
  for (int n = 0; n < 4; ++n) bv4[n] = bias[colw + n * 16 + fr];

#pragma unroll
  for (int m = 0; m < 2; ++m)
#pragma unroll
    for (int r = 0; r < 4; ++r) {
      int row = row0 + m * 16 + fq * 4 + r;
      u16* orow = QKV + (size_t)row * 768 + bn * 256 + colw;
#pragma unroll
      for (int n = 0; n < 4; ++n)
        orow[n * 16 + fr] = f32_to_bf16(acc[m][n][r] + bv4[n]);
    }
}

// ---------------------------------------------------------------------------
// Kernel 3: windowed attention (unchanged from round 1).
// ---------------------------------------------------------------------------
__global__ __launch_bounds__(256) void attn_kernel(const u16* __restrict__ QKV,
                                                   u16* __restrict__ AO) {
  const int S = 8192, NW = 1639, CH = 205;  // CH = ceil(1639/8)
  int wgid = blockIdx.x * 4 + (threadIdx.x >> 6);
  int lane = threadIdx.x & 63;
  int b = wgid / (4 * CH);
  int rm = wgid % (4 * CH);
  int h = rm / CH;
  int ch = rm % CH;
  int w = ch * 8 + (lane >> 3);
  int t = lane & 7;
  bool wv = (w < NW);

  float kv[5][8], vv[5][8];
#pragma unroll
  for (int j = 0; j < 5; ++j) {
    int s = w * 5 + j;
    if (wv && s < S) {
      size_t off = ((size_t)b * S + s) * 768 + h * 64 + t * 8;
      unpack8(*reinterpret_cast<const uint4*>(QKV + off + 256), kv[j]);
      unpack8(*reinterpret_cast<const uint4*>(QKV + off + 512), vv[j]);
    } else {
#pragma unroll
      for (int d = 0; d < 8; ++d) { kv[j][d] = 0.f; vv[j][d] = 0.f; }
    }
  }

#pragma unroll
  for (int i = 0; i < 5; ++i) {
    int s = w * 5 + i;
    bool sv = wv && (s < S);
    float q[8];
    if (sv) {
      size_t off = ((size_t)b * S + s) * 768 + h * 64 + t * 8;
      unpack8(*reinterpret_cast<const uint4*>(QKV + off), q);
    } else {
#pragma unroll
      for (int d = 0; d < 8; ++d) q[d] = 0.f;
    }
    float sc[5];
#pragma unroll
    for (int j = 0; j < 5; ++j) {
      float p = 0.f;
#pragma unroll
      for (int d = 0; d < 8; ++d) p += q[d] * kv[j][d];
      sc[j] = p;
    }
#pragma unroll
    for (int mask = 1; mask <= 4; mask <<= 1)
#pragma unroll
      for (int j = 0; j < 5; ++j) sc[j] += __shfl_xor(sc[j], mask);
#pragma unroll
    for (int j = 0; j < 5; ++j) sc[j] *= 0.125f;  // 1/sqrt(64)
    float mx = sc[0];
#pragma unroll
    for (int j = 1; j < 5; ++j) mx = fmaxf(mx, sc[j]);
    float e[5], sum = 0.f;
#pragma unroll
    for (int j = 0; j < 5; ++j) { e[j] = __expf(sc[j] - mx); sum += e[j]; }
    float inv = 1.0f / sum;
    float o[8];
#pragma unroll
    for (int d = 0; d < 8; ++d) {
      float a = 0.f;
#pragma unroll
      for (int j = 0; j < 5; ++j) a += e[j] * vv[j][d];
      float v2 = a * inv;
      float e2 = __expf(2.0f * v2);
      o[d] = 1.0f - 2.0f / (e2 + 1.0f);  // tanh
    }
    if (sv) {
      size_t oo = ((size_t)b * S + s) * 256 + h * 64 + t * 8;
      *reinterpret_cast<uint4*>(AO + oo) = pack8(o);
    }
  }
}

// ---------------------------------------------------------------------------
// Kernel 4: O-projection + bias + residual + LayerNorm, ZERO-LDS GEMM.
// Block = 32 rows x 256 cols, 4 waves n-split (wave 32x64, acc[2][4]).
// Only barrier: the LN cross-wave stat exchange (tiny LDS).
// ---------------------------------------------------------------------------
__global__ __launch_bounds__(256) void o_gemm_ln2(
    const u16* __restrict__ AO, const u16* __restrict__ Wob,
    const float* __restrict__ bo, const float* __restrict__ x,
    const float* __restrict__ gamma, const float* __restrict__ beta,
    float* __restrict__ out) {
  __shared__ float pS[4][32], pQ[4][32], muS[32], rsS[32];
  const int bm = blockIdx.x;   // 0..2047
  const int tid = threadIdx.x;
  const int lane = tid & 63;
  const int wid = tid >> 6;
  const int fr = lane & 15;
  const int fq = lane >> 4;
  const int row0 = bm * 32;
  const int col0 = wid * 64;

  const u16* Ag = AO + (size_t)(row0 + fr) * 256 + fq * 8;
  const u16* Bg = Wob + (size_t)(col0 + fr) * 256 + fq * 8;

  f32x4 acc[2][4] = {};

  for (int kt = 0; kt < 8; ++kt) {
    bf16x8 af[2], bf[4];
#pragma unroll
    for (int m = 0; m < 2; ++m)
      af[m] = *reinterpret_cast<const bf16x8*>(Ag + (size_t)(m * 16) * 256 + kt * 32);
#pragma unroll
    for (int n = 0; n < 4; ++n)
      bf[n] = *reinterpret_cast<const bf16x8*>(Bg + (size_t)(n * 16) * 256 + kt * 32);
#pragma unroll
    for (int m = 0; m < 2; ++m)
#pragma unroll
      for (int n = 0; n < 4; ++n)
        acc[m][n] = __builtin_amdgcn_mfma_f32_16x16x32_bf16(af[m], bf[n], acc[m][n], 0, 0, 0);
  }

  // epilogue: += bo + x (residual)
  float bov[4], gv[4], bev[4];
#pragma unroll
  for (int n = 0; n < 4; ++n) {
    int c = col0 + n * 16 + fr;
    bov[n] = bo[c]; gv[n] = gamma[c]; bev[n] = beta[c];
  }
#pragma unroll
  for (int m = 0; m < 2; ++m)
#pragma unroll
    for (int r = 0; r < 4; ++r) {
      size_t rg = (size_t)(row0 + m * 16 + fq * 4 + r);
#pragma unroll
      for (int n = 0; n < 4; ++n)
        acc[m][n][r] += bov[n] + x[rg * 256 + col0 + n * 16 + fr];
    }

  // LN stats: per (m,r) row, each wave reduces its 64-col quadrant
#pragma unroll
  for (int m = 0; m < 2; ++m)
#pragma unroll
    for (int r = 0; r < 4; ++r) {
      float s1 = 0.f, s2 = 0.f;
#pragma unroll
      for (int n = 0; n < 4; ++n) {
        float vx = acc[m][n][r];
        s1 += vx; s2 += vx * vx;
      }
#pragma unroll
      for (int mask = 1; mask <= 8; mask <<= 1) {
        s1 += __shfl_xor(s1, mask);
        s2 += __shfl_xor(s2, mask);
      }
      if (fr == 0) {
        int row = m * 16 + fq * 4 + r;   // 0..31
        pS[wid][row] = s1; pQ[wid][row] = s2;
      }
    }
  __syncthreads();
  if (tid < 32) {
    float s1 = pS[0][tid] + pS[1][tid] + pS[2][tid] + pS[3][tid];
    float s2 = pQ[0][tid] + pQ[1][tid] + pQ[2][tid] + pQ[3][tid];
    float mu = s1 * (1.0f / 256.0f);
    float var = s2 * (1.0f / 256.0f) - mu * mu;
    muS[tid] = mu;
    rsS[tid] = rsqrtf(var + 1e-5f);
  }
  __syncthreads();
#pragma unroll
  for (int m = 0; m < 2; ++m)
#pragma unroll
    for (int r = 0; r < 4; ++r) {
      int row = m * 16 + fq * 4 + r;
      float mu = muS[row], rs = rsS[row];
      float* orow = out + (size_t)(row0 + row) * 256;
#pragma unroll
      for (int n = 0; n < 4; ++n)
        orow[col0 + n * 16 + fr] = (acc[m][n][r] - mu) * rs * gv[n] + bev[n];
    }
}

// ---------------------------------------------------------------------------
extern "C" void kernel_launch(void* const* d_in, const int* in_sizes, int n_in,
                              void* d_out, int out_size, void* d_ws, size_t ws_size,
                              hipStream_t stream) {
  const float* x     = (const float*)d_in[0];
  const float* Wq    = (const float*)d_in[1];
  const float* bq    = (const float*)d_in[2];
  const float* Wk    = (const float*)d_in[3];
  const float* bk    = (const float*)d_in[4];
  const float* Wv    = (const float*)d_in[5];
  const float* bv    = (const float*)d_in[6];
  const float* Wo    = (const float*)d_in[7];
  const float* bo    = (const float*)d_in[8];
  const float* gamma = (const float*)d_in[9];
  const float* beta  = (const float*)d_in[10];
  float* out = (float*)d_out;

  char* ws = (char*)d_ws;
  u16* wqkv = (u16*)(ws);                 // 768x256 bf16  =    393,216 B
  u16* wob  = (u16*)(ws + 393216);        // 256x256 bf16  =    131,072 B
  u16* qkv  = (u16*)(ws + 524288);        // 65536x768 bf16= 100,663,296 B
  u16* ao   = (u16*)(ws + 101187584);     // 65536x256 bf16=  33,554,432 B
                                          // total ≈ 134.7 MiB

  convert_w<<<256, 256, 0, stream>>>(Wq, Wk, Wv, Wo, wqkv, wob);
  dim3 g1(3, 2048);
  qkv_gemm2<<<g1, 256, 0, stream>>>(x, wqkv, bq, bk, bv, qkv);
  attn_kernel<<<1640, 256, 0, stream>>>(qkv, ao);
  o_gemm_ln2<<<2048, 256, 0, stream>>>(ao, wob, bo, x, gamma, beta, out);
}

// Round 6
// 236.796 us; speedup vs baseline: 1.5998x; 1.5998x over previous
//
#include <hip/hip_runtime.h>
#include <hip/hip_bf16.h>
#include <stdint.h>

typedef unsigned short u16;
typedef __attribute__((ext_vector_type(8))) __bf16 bf16x8;
typedef __attribute__((ext_vector_type(4))) float f32x4;

#define DEV static __device__ __forceinline__

DEV u16 f32_to_bf16(float f) {
  uint32_t u = __float_as_uint(f);
  u += 0x7fffu + ((u >> 16) & 1u);   // round-to-nearest-even
  return (u16)(u >> 16);
}

DEV void unpack8(uint4 u, float* f) {
  uint32_t a[4] = {u.x, u.y, u.z, u.w};
#pragma unroll
  for (int i = 0; i < 4; ++i) {
    f[2 * i]     = __uint_as_float(a[i] << 16);
    f[2 * i + 1] = __uint_as_float(a[i] & 0xffff0000u);
  }
}

DEV uint4 pack8(const float* f) {
  uint32_t a[4];
#pragma unroll
  for (int i = 0; i < 4; ++i)
    a[i] = (uint32_t)f32_to_bf16(f[2 * i]) | ((uint32_t)f32_to_bf16(f[2 * i + 1]) << 16);
  return make_uint4(a[0], a[1], a[2], a[3]);
}

// async global->LDS, 16B per lane; LDS dest is wave-uniform-base + lane*16
DEV void gload16(const u16* g, u16* l) {
  __builtin_amdgcn_global_load_lds(
      (const __attribute__((address_space(1))) void*)g,
      (__attribute__((address_space(3))) void*)l, 16, 0, 0);
}

// ---------------------------------------------------------------------------
// Kernel 1: f32 -> bf16 of x (65536x256) and weights. wqkv = Wq|Wk|Wv rows.
// ---------------------------------------------------------------------------
__global__ __launch_bounds__(256) void convert_kernel(
    const float* __restrict__ x, const float* __restrict__ Wq,
    const float* __restrict__ Wk, const float* __restrict__ Wv,
    const float* __restrict__ Wo, u16* __restrict__ xb,
    u16* __restrict__ wqkv, u16* __restrict__ wob) {
  const size_t NX4 = (size_t)65536 * 256 / 4;
  size_t i = (size_t)blockIdx.x * 256 + threadIdx.x;
  const float* src;
  u16* dst;
  size_t off4;
  if (i < NX4) {
    src = x; dst = xb; off4 = i;
  } else {
    size_t w = i - NX4;
    int which = (int)(w >> 14);
    off4 = w & 16383;
    if (which == 0)      { src = Wq; dst = wqkv; }
    else if (which == 1) { src = Wk; dst = wqkv + 65536; }
    else if (which == 2) { src = Wv; dst = wqkv + 131072; }
    else                 { src = Wo; dst = wob; }
  }
  float4 v = reinterpret_cast<const float4*>(src)[off4];
  ushort4 o;
  o.x = f32_to_bf16(v.x); o.y = f32_to_bf16(v.y);
  o.z = f32_to_bf16(v.z); o.w = f32_to_bf16(v.w);
  reinterpret_cast<ushort4*>(dst)[off4] = o;
}

// ---------------------------------------------------------------------------
// Kernel 2: QKV GEMM, m97 structure.  C(65536x768) = Xb @ Wqkv^T + bias.
// 128x128 tile, BK=32, 4 waves (2x2), global_load_lds width-16 staging.
// LDS [128][32] bf16 linear; chunk-XOR swizzle (c ^= row&3) applied on the
// GLOBAL source and on the ds_read address (both-sides involution) to cut
// ds_read_b128 bank conflicts to the b128 floor.
// ---------------------------------------------------------------------------
__global__ __launch_bounds__(256) void qkv_gemm3(
    const u16* __restrict__ Xb, const u16* __restrict__ Wqkv,
    const float* __restrict__ bq, const float* __restrict__ bk,
    const float* __restrict__ bv, u16* __restrict__ QKV) {
  __shared__ __align__(16) u16 As[128 * 32];
  __shared__ __align__(16) u16 Bs[128 * 32];
  const int bid = blockIdx.x;                 // 3072 blocks, %8==0
  const int swz = (bid & 7) * 384 + (bid >> 3);  // XCD-contiguous
  const int bn = swz % 6;
  const int bm = swz / 6;
  const int tid = threadIdx.x;
  const int lane = tid & 63;
  const int wid = tid >> 6;
  const int wm = (wid >> 1) * 64;
  const int wn = (wid & 1) * 64;
  const int fr = lane & 15;
  const int fq = lane >> 4;

  // staging: 512 chunks of 16B per tile, 2 per thread. chunk c -> LDS c*16B,
  // global row=c>>2, colchunk=(c&3)^((c>>2)&3)  (inverse swizzle on source)
  const int c0 = tid, c1 = tid + 256;
  const int r0c = c0 >> 2, s0 = (c0 ^ (c0 >> 2)) & 3;
  const int r1c = c1 >> 2, s1 = (c1 ^ (c1 >> 2)) & 3;
  const u16* Ag0 = Xb + (size_t)(bm * 128 + r0c) * 256 + s0 * 8;
  const u16* Ag1 = Xb + (size_t)(bm * 128 + r1c) * 256 + s1 * 8;
  const u16* Bg0 = Wqkv + (size_t)(bn * 128 + r0c) * 256 + s0 * 8;
  const u16* Bg1 = Wqkv + (size_t)(bn * 128 + r1c) * 256 + s1 * 8;
  u16* lA0 = As + c0 * 8;
  u16* lA1 = As + c1 * 8;
  u16* lB0 = Bs + c0 * 8;
  u16* lB1 = Bs + c1 * 8;

  f32x4 acc[4][4] = {};

  for (int kt = 0; kt < 8; ++kt) {
    gload16(Ag0 + kt * 32, lA0);
    gload16(Ag1 + kt * 32, lA1);
    gload16(Bg0 + kt * 32, lB0);
    gload16(Bg1 + kt * 32, lB1);
    __syncthreads();          // drains vmcnt -> staged data visible
    bf16x8 af[4], bf[4];
#pragma unroll
    for (int m = 0; m < 4; ++m) {
      int row = wm + m * 16 + fr;
      af[m] = *reinterpret_cast<const bf16x8*>(As + row * 32 + ((fq ^ (row & 3)) * 8));
    }
#pragma unroll
    for (int n = 0; n < 4; ++n) {
      int row = wn + n * 16 + fr;
      bf[n] = *reinterpret_cast<const bf16x8*>(Bs + row * 32 + ((fq ^ (row & 3)) * 8));
    }
#pragma unroll
    for (int m = 0; m < 4; ++m)
#pragma unroll
      for (int n = 0; n < 4; ++n)
        acc[m][n] = __builtin_amdgcn_mfma_f32_16x16x32_bf16(af[m], bf[n], acc[m][n], 0, 0, 0);
    __syncthreads();          // before next stage overwrites
  }

  const float* bias = (bn < 2) ? (bq + (bn & 1) * 128)
                    : (bn < 4) ? (bk + ((bn - 2) & 1) * 128)
                               : (bv + ((bn - 4) & 1) * 128);
  float bv4[4];
#pragma unroll
  for (int n = 0; n < 4; ++n) bv4[n] = bias[wn + n * 16 + fr];

#pragma unroll
  for (int m = 0; m < 4; ++m)
#pragma unroll
    for (int r = 0; r < 4; ++r) {
      int row = bm * 128 + wm + m * 16 + fq * 4 + r;
      u16* orow = QKV + (size_t)row * 768 + bn * 128;
#pragma unroll
      for (int n = 0; n < 4; ++n)
        orow[wn + n * 16 + fr] = f32_to_bf16(acc[m][n][r] + bv4[n]);
    }
}

// ---------------------------------------------------------------------------
// Kernel 3: windowed attention (unchanged; correct at absmax 0.031).
// ---------------------------------------------------------------------------
__global__ __launch_bounds__(256) void attn_kernel(const u16* __restrict__ QKV,
                                                   u16* __restrict__ AO) {
  const int S = 8192, NW = 1639, CH = 205;
  int wgid = blockIdx.x * 4 + (threadIdx.x >> 6);
  int lane = threadIdx.x & 63;
  int b = wgid / (4 * CH);
  int rm = wgid % (4 * CH);
  int h = rm / CH;
  int ch = rm % CH;
  int w = ch * 8 + (lane >> 3);
  int t = lane & 7;
  bool wv = (w < NW);

  float kv[5][8], vv[5][8];
#pragma unroll
  for (int j = 0; j < 5; ++j) {
    int s = w * 5 + j;
    if (wv && s < S) {
      size_t off = ((size_t)b * S + s) * 768 + h * 64 + t * 8;
      unpack8(*reinterpret_cast<const uint4*>(QKV + off + 256), kv[j]);
      unpack8(*reinterpret_cast<const uint4*>(QKV + off + 512), vv[j]);
    } else {
#pragma unroll
      for (int d = 0; d < 8; ++d) { kv[j][d] = 0.f; vv[j][d] = 0.f; }
    }
  }

#pragma unroll
  for (int i = 0; i < 5; ++i) {
    int s = w * 5 + i;
    bool sv = wv && (s < S);
    float q[8];
    if (sv) {
      size_t off = ((size_t)b * S + s) * 768 + h * 64 + t * 8;
      unpack8(*reinterpret_cast<const uint4*>(QKV + off), q);
    } else {
#pragma unroll
      for (int d = 0; d < 8; ++d) q[d] = 0.f;
    }
    float sc[5];
#pragma unroll
    for (int j = 0; j < 5; ++j) {
      float p = 0.f;
#pragma unroll
      for (int d = 0; d < 8; ++d) p += q[d] * kv[j][d];
      sc[j] = p;
    }
#pragma unroll
    for (int mask = 1; mask <= 4; mask <<= 1)
#pragma unroll
      for (int j = 0; j < 5; ++j) sc[j] += __shfl_xor(sc[j], mask);
#pragma unroll
    for (int j = 0; j < 5; ++j) sc[j] *= 0.125f;
    float mx = sc[0];
#pragma unroll
    for (int j = 1; j < 5; ++j) mx = fmaxf(mx, sc[j]);
    float e[5], sum = 0.f;
#pragma unroll
    for (int j = 0; j < 5; ++j) { e[j] = __expf(sc[j] - mx); sum += e[j]; }
    float inv = 1.0f / sum;
    float o[8];
#pragma unroll
    for (int d = 0; d < 8; ++d) {
      float a = 0.f;
#pragma unroll
      for (int j = 0; j < 5; ++j) a += e[j] * vv[j][d];
      float v2 = a * inv;
      float e2 = __expf(2.0f * v2);
      o[d] = 1.0f - 2.0f / (e2 + 1.0f);
    }
    if (sv) {
      size_t oo = ((size_t)b * S + s) * 256 + h * 64 + t * 8;
      *reinterpret_cast<uint4*>(AO + oo) = pack8(o);
    }
  }
}

// ---------------------------------------------------------------------------
// Kernel 4: O-proj + bias + residual + LN, m97 structure.
// 64x256 tile (full row -> LN fused), 4 n-split waves, acc[4][4].
// Same staging + swizzle scheme as qkv_gemm3.
// ---------------------------------------------------------------------------
__global__ __launch_bounds__(256) void o_gemm_ln3(
    const u16* __restrict__ AO, const u16* __restrict__ Wob,
    const float* __restrict__ bo, const float* __restrict__ x,
    const float* __restrict__ gamma, const float* __restrict__ beta,
    float* __restrict__ out) {
  __shared__ __align__(16) u16 As[64 * 32];    // 4 KB
  __shared__ __align__(16) u16 Bs[256 * 32];   // 16 KB
  __shared__ float pS[4][64], pQ[4][64], muS[64], rsS[64];
  const int bm = blockIdx.x;   // 0..1023
  const int tid = threadIdx.x;
  const int lane = tid & 63;
  const int wid = tid >> 6;
  const int wn = wid * 64;
  const int fr = lane & 15;
  const int fq = lane >> 4;
  const int row0 = bm * 64;

  // A: 256 chunks (1/thread); B: 1024 chunks (4/thread)
  const int ra = tid >> 2, sa = (tid ^ (tid >> 2)) & 3;
  const u16* Ag = AO + (size_t)(row0 + ra) * 256 + sa * 8;
  u16* lA = As + tid * 8;
  const u16* Bg0 = Wob + (size_t)((tid) >> 2) * 256 + (((tid) ^ ((tid) >> 2)) & 3) * 8;
  const u16* Bg1 = Wob + (size_t)((tid + 256) >> 2) * 256 + (((tid + 256) ^ ((tid + 256) >> 2)) & 3) * 8;
  const u16* Bg2 = Wob + (size_t)((tid + 512) >> 2) * 256 + (((tid + 512) ^ ((tid + 512) >> 2)) & 3) * 8;
  const u16* Bg3 = Wob + (size_t)((tid + 768) >> 2) * 256 + (((tid + 768) ^ ((tid + 768) >> 2)) & 3) * 8;
  u16* lB0 = Bs + tid * 8;
  u16* lB1 = Bs + (tid + 256) * 8;
  u16* lB2 = Bs + (tid + 512) * 8;
  u16* lB3 = Bs + (tid + 768) * 8;

  f32x4 acc[4][4] = {};

  for (int kt = 0; kt < 8; ++kt) {
    gload16(Ag + kt * 32, lA);
    gload16(Bg0 + kt * 32, lB0);
    gload16(Bg1 + kt * 32, lB1);
    gload16(Bg2 + kt * 32, lB2);
    gload16(Bg3 + kt * 32, lB3);
    __syncthreads();
    bf16x8 af[4], bf[4];
#pragma unroll
    for (int m = 0; m < 4; ++m) {
      int row = m * 16 + fr;
      af[m] = *reinterpret_cast<const bf16x8*>(As + row * 32 + ((fq ^ (row & 3)) * 8));
    }
#pragma unroll
    for (int n = 0; n < 4; ++n) {
      int row = wn + n * 16 + fr;
      bf[n] = *reinterpret_cast<const bf16x8*>(Bs + row * 32 + ((fq ^ (row & 3)) * 8));
    }
#pragma unroll
    for (int m = 0; m < 4; ++m)
#pragma unroll
      for (int n = 0; n < 4; ++n)
        acc[m][n] = __builtin_amdgcn_mfma_f32_16x16x32_bf16(af[m], bf[n], acc[m][n], 0, 0, 0);
    __syncthreads();
  }

  // epilogue: += bo + x (residual)
  float bov[4], gv[4], bev[4];
#pragma unroll
  for (int n = 0; n < 4; ++n) {
    int c = wn + n * 16 + fr;
    bov[n] = bo[c]; gv[n] = gamma[c]; bev[n] = beta[c];
  }
#pragma unroll
  for (int m = 0; m < 4; ++m)
#pragma unroll
    for (int r = 0; r < 4; ++r) {
      size_t rg = (size_t)(row0 + m * 16 + fq * 4 + r);
#pragma unroll
      for (int n = 0; n < 4; ++n)
        acc[m][n][r] += bov[n] + x[rg * 256 + wn + n * 16 + fr];
    }

  // LN stats per row (rows 0..63 within block, shared by all 4 n-waves)
#pragma unroll
  for (int m = 0; m < 4; ++m)
#pragma unroll
    for (int r = 0; r < 4; ++r) {
      float s1 = 0.f, s2 = 0.f;
#pragma unroll
      for (int n = 0; n < 4; ++n) {
        float vx = acc[m][n][r];
        s1 += vx; s2 += vx * vx;
      }
#pragma unroll
      for (int mask = 1; mask <= 8; mask <<= 1) {
        s1 += __shfl_xor(s1, mask);
        s2 += __shfl_xor(s2, mask);
      }
      if (fr == 0) {
        int row = m * 16 + fq * 4 + r;   // 0..63
        pS[wid][row] = s1; pQ[wid][row] = s2;
      }
    }
  __syncthreads();
  if (tid < 64) {
    float s1 = pS[0][tid] + pS[1][tid] + pS[2][tid] + pS[3][tid];
    float s2 = pQ[0][tid] + pQ[1][tid] + pQ[2][tid] + pQ[3][tid];
    float mu = s1 * (1.0f / 256.0f);
    float var = s2 * (1.0f / 256.0f) - mu * mu;
    muS[tid] = mu;
    rsS[tid] = rsqrtf(var + 1e-5f);
  }
  __syncthreads();
#pragma unroll
  for (int m = 0; m < 4; ++m)
#pragma unroll
    for (int r = 0; r < 4; ++r) {
      int row = m * 16 + fq * 4 + r;
      float mu = muS[row], rs = rsS[row];
      float* orow = out + (size_t)(row0 + row) * 256;
#pragma unroll
      for (int n = 0; n < 4; ++n)
        orow[wn + n * 16 + fr] = (acc[m][n][r] - mu) * rs * gv[n] + bev[n];
    }
}

// ---------------------------------------------------------------------------
extern "C" void kernel_launch(void* const* d_in, const int* in_sizes, int n_in,
                              void* d_out, int out_size, void* d_ws, size_t ws_size,
                              hipStream_t stream) {
  const float* x     = (const float*)d_in[0];
  const float* Wq    = (const float*)d_in[1];
  const float* bq    = (const float*)d_in[2];
  const float* Wk    = (const float*)d_in[3];
  const float* bk    = (const float*)d_in[4];
  const float* Wv    = (const float*)d_in[5];
  const float* bv    = (const float*)d_in[6];
  const float* Wo    = (const float*)d_in[7];
  const float* bo    = (const float*)d_in[8];
  const float* gamma = (const float*)d_in[9];
  const float* beta  = (const float*)d_in[10];
  float* out = (float*)d_out;

  char* ws = (char*)d_ws;
  u16* xb   = (u16*)(ws);                    // 65536x256 bf16
  u16* wqkv = (u16*)(ws + 33554432);         // 768x256 bf16
  u16* wob  = (u16*)(ws + 33947648);         // 256x256 bf16
  u16* qkv  = (u16*)(ws + 34078720);         // 65536x768 bf16
  u16* ao   = (u16*)(ws + 134742016);        // 65536x256 bf16

  convert_kernel<<<16640, 256, 0, stream>>>(x, Wq, Wk, Wv, Wo, xb, wqkv, wob);
  qkv_gemm3<<<3072, 256, 0, stream>>>(xb, wqkv, bq, bk, bv, qkv);
  attn_kernel<<<1640, 256, 0, stream>>>(qkv, ao);
  o_gemm_ln3<<<1024, 256, 0, stream>>>(ao, wob, bo, x, gamma, beta, out);
}